// Round 8
// baseline (6552.838 us; speedup 1.0000x reference)
//
#include <hip/hip_runtime.h>
#include <hip/hip_bf16.h>

#define Bv 64
#define Tv 512
#define Iv 1024
#define Hv 1024
#define G4v 4096
#define NHB 64          // recurrent blocks
#define NXB 128         // producer blocks (2 per 64-col slice, row-split)
#define NBLK (NHB + NXB)
#define DEPTH 8         // xg ring depth (power of 2)
#define FSTR 16         // flag padding: 64B

typedef __attribute__((ext_vector_type(8))) short bf16x8;
typedef __attribute__((ext_vector_type(4))) float f32x4;

#define LOADC(p)    __hip_atomic_load((p), __ATOMIC_RELAXED, __HIP_MEMORY_SCOPE_AGENT)
#define STOREC(p,v) __hip_atomic_store((p), (v), __ATOMIC_RELAXED, __HIP_MEMORY_SCOPE_AGENT)

__device__ __forceinline__ float sigmoid_f(float v) { return 1.f / (1.f + __expf(-v)); }
__device__ __forceinline__ float tanh_f(float v) { return 1.f - 2.f / (__expf(2.f * v) + 1.f); }

// ---------------- prep: weights -> bf16, bias sum, zero h ping-pong + flags ----------------
__global__ void prep(const float* __restrict__ w_ih, const float* __restrict__ w_hh,
                     const float* __restrict__ b_ih, const float* __restrict__ b_hh,
                     __hip_bfloat16* __restrict__ wbih, __hip_bfloat16* __restrict__ wbhh,
                     float* __restrict__ bias, __hip_bfloat16* __restrict__ hbuf,
                     unsigned* __restrict__ hflag, unsigned* __restrict__ xflag) {
  unsigned i = blockIdx.x * 256u + threadIdx.x;   // grid covers exactly 4096*1024
  wbih[i] = __float2bfloat16(w_ih[i]);
  wbhh[i] = __float2bfloat16(w_hh[i]);
  if (i < (unsigned)G4v) bias[i] = b_ih[i] + b_hh[i];
  if (i < 2u * Bv * Hv) hbuf[i] = __float2bfloat16(0.f);
  if (i < (unsigned)(NHB * FSTR)) hflag[i] = 0u;
  if (i < (unsigned)(NXB * FSTR)) xflag[i] = 0u;
}

// MFMA over a 4-kstep chunk, A from the aq[] burst registers (static indices).
#define MFMA4(cc)                                                       \
  _Pragma("unroll")                                                     \
  for (int j = 0; j < 4; ++j) {                                         \
    int k0 = (((cc) * 4 + j) << 5) + lk;                                \
    union { unsigned long long q[2]; bf16x8 v; } ua;                    \
    ua.q[0] = aq[((cc) * 4 + j) * 2]; ua.q[1] = aq[((cc) * 4 + j) * 2 + 1]; \
    _Pragma("unroll")                                                   \
    for (int nf = 0; nf < 4; ++nf) {                                    \
      int n = nf * 16 + lrow;                                           \
      unsigned byt = (unsigned)((n << 11) + (k0 << 1)) ^ ((unsigned)(n & 7) << 4); \
      bf16x8 b = *(const bf16x8*)(&lds[byt]);                           \
      acc[nf] = __builtin_amdgcn_mfma_f32_16x16x32_bf16(ua.v, b, acc[nf], 0, 0, 0); \
    }                                                                   \
  }

// ---------------- persistent dataflow LSTM (no grid barrier, no fences) ----------------
// blocks 0..63: h-blocks (own 16 h-cols = 64 gate-cols). blocks 64..191: x-blocks.
// All cross-block traffic via agent-scope (sc1) loads/stores: writers write-through
// to LLC, readers bypass L1/L2 -> no acquire fence, L2 never invalidated.
// hflag[b] = steps completed by h-block b. xflag[j] = steps produced by x-block j.
// xg ring: DEPTH slots; h step t reads slot t&7 (needs xflag[2wg..2wg+1] >= t+1);
// x step t writes slot t&7 (needs all hflag >= t-DEPTH+1, i.e. slot consumed).
__global__ void __launch_bounds__(256, 1) lstm_main(
    const float* __restrict__ x,
    const __hip_bfloat16* __restrict__ wbih,
    const __hip_bfloat16* __restrict__ wbhh,
    const float* __restrict__ bias,
    __hip_bfloat16* __restrict__ hbuf,   // [2][B][H] bf16 ping-pong (sc1)
    float* __restrict__ xg,              // [DEPTH][B][4H] f32 ring (sc1)
    float* __restrict__ out,             // B*T*H + B*H + B*H
    unsigned* __restrict__ hflag,
    unsigned* __restrict__ xflag)
{
  extern __shared__ char lds[];
  float* gbuf = (float*)(lds + 131072);

  const int bid  = blockIdx.x;
  const bool is_h = (bid < NHB);
  const int tid  = threadIdx.x;
  const int lane = tid & 63;
  const int wave = tid >> 6;
  const int lrow = lane & 15;        // A row / B,D col within fragment
  const int lkg  = lane >> 4;        // 0..3
  const int lk   = lkg * 8;          // k offset within 32

  const int wg = is_h ? bid : ((bid - NHB) >> 1);   // gate-col slice 0..63
  const int rh = is_h ? 0 : ((bid - NHB) & 1);      // x row-half

  // ---- stage this block's 64x1024 weight slice into LDS (once, swizzled) ----
  {
    const __hip_bfloat16* wsrc = is_h ? wbhh : wbih;
    for (int c = tid; c < 8192; c += 256) {       // 8192 chunks of 16B = 128KB
      int n   = c >> 7;                           // local col 0..63
      int k16 = c & 127;                          // 16B chunk in k
      int gc  = ((n >> 4) << 10) + (wg << 4) + (n & 15);   // global gate row
      uint4 v = *(const uint4*)(wsrc + ((size_t)gc << 10) + (k16 << 3));
      unsigned byt = (unsigned)((n << 11) + (k16 << 4)) ^ ((unsigned)(n & 7) << 4);
      *(uint4*)(&lds[byt]) = v;
    }
  }
  __syncthreads();

  if (!is_h) {
    // ================= x-producer block: 32 rows x 64 gate-cols per step =================
    const int j  = bid - NHB;
    const int wr = wave & 1;       // 16-row tile within the 32-row half
    const int wc = wave >> 1;      // 32-col half
    const int arow = rh * 32 + wr * 16 + lrow;     // batch row for A loads
    const float* xa = x + (size_t)arow * (Tv * Iv) + lk;

    for (int t = 0; t < Tv; ++t) {
      if (t >= DEPTH) {            // slot t&7 must be consumed: all hflag >= t-DEPTH+1
        const unsigned tgt = (unsigned)(t - DEPTH + 1);
        for (;;) {
          unsigned hf = LOADC(&hflag[lane * FSTR]);
          if (__all(hf >= tgt)) break;
          __builtin_amdgcn_s_sleep(2);
        }
        asm volatile("" ::: "memory");
      }
      f32x4 acc[2];
      acc[0] = f32x4{0.f,0.f,0.f,0.f}; acc[1] = f32x4{0.f,0.f,0.f,0.f};
      const float* xt = xa + (size_t)t * Iv;
      #pragma unroll 4
      for (int ks = 0; ks < 32; ++ks) {
        int k0 = (ks << 5) + lk;
        float4 f0 = *(const float4*)(xt + (ks << 5));
        float4 f1 = *(const float4*)(xt + (ks << 5) + 4);
        union { __hip_bfloat16 e[8]; bf16x8 v; } u;
        u.e[0] = __float2bfloat16(f0.x); u.e[1] = __float2bfloat16(f0.y);
        u.e[2] = __float2bfloat16(f0.z); u.e[3] = __float2bfloat16(f0.w);
        u.e[4] = __float2bfloat16(f1.x); u.e[5] = __float2bfloat16(f1.y);
        u.e[6] = __float2bfloat16(f1.z); u.e[7] = __float2bfloat16(f1.w);
        bf16x8 b0, b1;
        {
          int n = wc * 32 + lrow;
          unsigned byt = (unsigned)((n << 11) + (k0 << 1)) ^ ((unsigned)(n & 7) << 4);
          b0 = *(const bf16x8*)(&lds[byt]);
          n += 16;
          byt = (unsigned)((n << 11) + (k0 << 1)) ^ ((unsigned)(n & 7) << 4);
          b1 = *(const bf16x8*)(&lds[byt]);
        }
        acc[0] = __builtin_amdgcn_mfma_f32_16x16x32_bf16(u.v, b0, acc[0], 0, 0, 0);
        acc[1] = __builtin_amdgcn_mfma_f32_16x16x32_bf16(u.v, b1, acc[1], 0, 0, 0);
      }
      float* dst = xg + (size_t)(t & (DEPTH - 1)) * (Bv * G4v);
      for (int nf = 0; nf < 2; ++nf) {
        int gc  = (wc * 2 + nf) * 1024 + (wg << 4) + lrow;   // global gate col
        int row = rh * 32 + wr * 16 + (lkg << 2);
        for (int r = 0; r < 4; ++r)
          STOREC(&dst[(size_t)(row + r) * G4v + gc], acc[nf][r]);
      }
      asm volatile("s_waitcnt vmcnt(0)" ::: "memory");
      __syncthreads();
      if (tid == 0) STOREC(&xflag[j * FSTR], (unsigned)(t + 1));
      __syncthreads();
    }
    return;
  }

  // ================= h-recurrent block: full h x 64 gate-cols per step =================
  const int eb  = tid >> 2;            // batch row 0..63 (elementwise)
  const int ec0 = (tid & 3) << 2;      // h-col offset base within 16
  float c_state[4] = {0.f, 0.f, 0.f, 0.f};
  float biasv[16];
  for (int g = 0; g < 4; ++g)
    for (int jj = 0; jj < 4; ++jj)
      biasv[g * 4 + jj] = bias[(g << 10) + (wg << 4) + ec0 + jj];

  const int ar = wave * 16 + lrow;     // A row this lane loads (16 rows per wave)

  for (int t = 0; t < Tv; ++t) {
    // ---- phase 1: xg producer check (they run ~DEPTH ahead -> usually instant) ----
    {
      const unsigned xtg = (unsigned)(t + 1);
      const unsigned* xf = &xflag[(2 * wg + (lane & 1)) * FSTR];
      for (;;) {
        unsigned xv = LOADC(xf);
        if (__all(xv >= xtg)) break;
      }
      asm volatile("" ::: "memory");
    }
    // ---- phase 2: ISSUE xg loads now; their LLC trip rides under the hflag poll ----
    float xgv[16];
    {
      const unsigned long long* xq = (const unsigned long long*)
          (xg + (size_t)(t & (DEPTH - 1)) * (Bv * G4v) + (size_t)eb * G4v + (wg << 4) + ec0);
      #pragma unroll
      for (int g = 0; g < 4; ++g) {
        union { unsigned long long q[2]; float f[4]; } ux;
        ux.q[0] = LOADC(xq + g * 512);
        ux.q[1] = LOADC(xq + g * 512 + 1);
        xgv[g * 4 + 0] = ux.f[0]; xgv[g * 4 + 1] = ux.f[1];
        xgv[g * 4 + 2] = ux.f[2]; xgv[g * 4 + 3] = ux.f[3];
      }
    }
    // ---- phase 3: poll all h-blocks done step t-1 (tight spin, one load in flight) ----
    {
      const unsigned ht = (unsigned)t;
      for (;;) {
        unsigned hf = LOADC(&hflag[lane * FSTR]);
        if (__all(hf >= ht)) break;
      }
      asm volatile("" ::: "memory");
    }
    // ---- phase 4: FULL A burst: 64x8B sc1 loads, all in flight -> one LLC trip ----
    // aq[64] = 128 VGPRs, static indices only (rule #20). Launch fallback protects
    // against coop-launch VGPR validation (R5/R6 lesson).
    const __hip_bfloat16* hp = hbuf + (size_t)((t + 1) & 1) * (Bv * Hv);
    const unsigned long long* hq = (const unsigned long long*)hp + (size_t)ar * 256 + lkg * 2;
    unsigned long long aq[64];
    #pragma unroll
    for (int ks = 0; ks < 32; ++ks) {
      aq[2 * ks]     = LOADC(hq + ks * 8);
      aq[2 * ks + 1] = LOADC(hq + ks * 8 + 1);
    }
    f32x4 acc[4];
    for (int nf = 0; nf < 4; ++nf) acc[nf] = f32x4{0.f,0.f,0.f,0.f};
    MFMA4(0) MFMA4(1) MFMA4(2) MFMA4(3)
    MFMA4(4) MFMA4(5) MFMA4(6) MFMA4(7)
    // ---- exchange gates through LDS ----
    #pragma unroll
    for (int nf = 0; nf < 4; ++nf)
      for (int r = 0; r < 4; ++r)
        gbuf[(wave * 16 + (lkg << 2) + r) * 65 + nf * 16 + lrow] = acc[nf][r];
    __syncthreads();
    float hv[4];
    #pragma unroll
    for (int jj = 0; jj < 4; ++jj) {
      int cc = ec0 + jj;
      float g0 = gbuf[eb * 65 +      cc] + xgv[0 + jj]  + biasv[0 + jj];
      float g1 = gbuf[eb * 65 + 16 + cc] + xgv[4 + jj]  + biasv[4 + jj];
      float g2 = gbuf[eb * 65 + 32 + cc] + xgv[8 + jj]  + biasv[8 + jj];
      float g3 = gbuf[eb * 65 + 48 + cc] + xgv[12 + jj] + biasv[12 + jj];
      float ig = sigmoid_f(g0);
      float fg = sigmoid_f(g1);
      float gg = tanh_f(g2);
      float og = sigmoid_f(g3);
      float cv = fg * c_state[jj] + ig * gg;
      c_state[jj] = cv;
      hv[jj] = og * tanh_f(cv);
    }
    // publish h slice (one 8B sc1 store); drain covers ONLY this store
    __hip_bfloat16* hw = hbuf + (size_t)(t & 1) * (Bv * Hv) + ((size_t)eb << 10) + (wg << 4) + ec0;
    union { __hip_bfloat16 h[4]; unsigned long long q; } hu;
    for (int jj = 0; jj < 4; ++jj) hu.h[jj] = __float2bfloat16(hv[jj]);
    STOREC((unsigned long long*)hw, hu.q);
    asm volatile("s_waitcnt vmcnt(0)" ::: "memory");
    __syncthreads();                    // all waves' h stores at LLC
    if (tid == 0) STOREC(&hflag[wg * FSTR], (unsigned)(t + 1));
    // ---- out stores AFTER flag publish: HBM ack off the critical path ----
    float* ow = out + (size_t)eb * (Tv * Hv) + ((size_t)t << 10) + (wg << 4) + ec0;
    f32x4 ov = {hv[0], hv[1], hv[2], hv[3]};
    __builtin_nontemporal_store(ov, (f32x4*)ow);
    if (t == Tv - 1) {
      float* hn = out + (size_t)Bv * Tv * Hv + ((size_t)eb << 10) + (wg << 4) + ec0;
      float* cn = hn + (size_t)Bv * Hv;
      for (int jj = 0; jj < 4; ++jj) { hn[jj] = hv[jj]; cn[jj] = c_state[jj]; }
    }
    __syncthreads();
  }
}

// ---------------- host launch ----------------
extern "C" void kernel_launch(void* const* d_in, const int* in_sizes, int n_in,
                              void* d_out, int out_size, void* d_ws, size_t ws_size,
                              hipStream_t stream) {
  const float* x    = (const float*)d_in[0];
  const float* w_ih = (const float*)d_in[1];
  const float* b_ih = (const float*)d_in[2];
  const float* w_hh = (const float*)d_in[3];
  const float* b_hh = (const float*)d_in[4];
  float* out = (float*)d_out;

  char* ws = (char*)d_ws;
  __hip_bfloat16* wbih = (__hip_bfloat16*)(ws);                        // 8 MB
  __hip_bfloat16* wbhh = (__hip_bfloat16*)(ws + ((size_t)8 << 20));    // 8 MB
  float*          bias = (float*)(ws + ((size_t)16 << 20));            // 16 KB
  __hip_bfloat16* hbuf = (__hip_bfloat16*)(ws + ((size_t)16 << 20) + 65536); // 256 KB
  float*          xg   = (float*)(ws + ((size_t)18 << 20));            // 8 MB ring
  unsigned*       hflag= (unsigned*)(ws + ((size_t)26 << 20));         // 4 KB
  unsigned*       xflag= (unsigned*)(ws + ((size_t)26 << 20) + 8192);  // 8 KB

  hipLaunchKernelGGL(prep, dim3(16384), dim3(256), 0, stream,
                     w_ih, w_hh, b_ih, b_hh, wbih, wbhh, bias, hbuf, hflag, xflag);

  const unsigned ldsBytes = 131072u + 64u * 65u * 4u;  // 147712
  hipFuncSetAttribute((const void*)lstm_main,
                      hipFuncAttributeMaxDynamicSharedMemorySize, (int)ldsBytes);

  const float* xA = x;
  const __hip_bfloat16* wbihA = wbih;
  const __hip_bfloat16* wbhhA = wbhh;
  const float* biasA = bias;
  __hip_bfloat16* hbufA = hbuf;
  float* xgA = xg;
  float* outA = out;
  unsigned* hflagA = hflag;
  unsigned* xflagA = xflag;
  void* args[9] = {(void*)&xA, (void*)&wbihA, (void*)&wbhhA, (void*)&biasA,
                   (void*)&hbufA, (void*)&xgA, (void*)&outA, (void*)&hflagA, (void*)&xflagA};

  // Cooperative launch guarantees co-residency, but its validation can reject
  // silently (R5/R6 zero-output signature). Our sync protocol uses only our own
  // flags (no cg::grid.sync), and 147712B LDS forces 1 block/CU so 192 blocks
  // co-reside under a plain launch too. Fall back if coop launch errors.
  hipError_t lerr = hipLaunchCooperativeKernel((const void*)lstm_main, dim3(NBLK),
                                               dim3(256), args, ldsBytes, stream);
  if (lerr != hipSuccess) {
    (void)hipGetLastError();   // clear sticky error, then plain launch
    hipLaunchKernelGGL(lstm_main, dim3(NBLK), dim3(256), ldsBytes, stream,
                       xA, wbihA, wbhhA, biasA, hbufA, xgA, outA, hflagA, xflagA);
  }
}

// Round 9
// 5336.924 us; speedup vs baseline: 1.2278x; 1.2278x over previous
//
#include <hip/hip_runtime.h>
#include <hip/hip_bf16.h>

#define Bv 64
#define Tv 512
#define Iv 1024
#define Hv 1024
#define G4v 4096
#define NHB 64          // recurrent blocks
#define NXB 128         // producer blocks (2 per 64-col slice, row-split)
#define NBLK (NHB + NXB)
#define DEPTH 8         // xg ring depth (power of 2)
#define FSTR 16         // flag padding: 64B

typedef __attribute__((ext_vector_type(8))) short bf16x8;
typedef __attribute__((ext_vector_type(4))) float f32x4;

#define LOADC(p)    __hip_atomic_load((p), __ATOMIC_RELAXED, __HIP_MEMORY_SCOPE_AGENT)
#define STOREC(p,v) __hip_atomic_store((p), (v), __ATOMIC_RELAXED, __HIP_MEMORY_SCOPE_AGENT)

__device__ __forceinline__ float sigmoid_f(float v) { return 1.f / (1.f + __expf(-v)); }
__device__ __forceinline__ float tanh_f(float v) { return 1.f - 2.f / (__expf(2.f * v) + 1.f); }

// ---------------- prep: weights -> bf16, bias sum, zero h ping-pong + flags ----------------
__global__ void prep(const float* __restrict__ w_ih, const float* __restrict__ w_hh,
                     const float* __restrict__ b_ih, const float* __restrict__ b_hh,
                     __hip_bfloat16* __restrict__ wbih, __hip_bfloat16* __restrict__ wbhh,
                     float* __restrict__ bias, __hip_bfloat16* __restrict__ hbuf,
                     unsigned* __restrict__ hflag, unsigned* __restrict__ xflag) {
  unsigned i = blockIdx.x * 256u + threadIdx.x;   // grid covers exactly 4096*1024
  wbih[i] = __float2bfloat16(w_ih[i]);
  wbhh[i] = __float2bfloat16(w_hh[i]);
  if (i < (unsigned)G4v) bias[i] = b_ih[i] + b_hh[i];
  if (i < 2u * Bv * Hv) hbuf[i] = __float2bfloat16(0.f);
  if (i < (unsigned)(NHB * FSTR)) hflag[i] = 0u;
  if (i < (unsigned)(NXB * FSTR)) xflag[i] = 0u;
}

// A-chunk pipeline: chunk = 4 k-steps = 8 x 8B sc1 loads into a NAMED register
// buffer (16 VGPRs each; static indices only). 2 buffers ping-pong.
#define LOAD4(buf, cc)                                                  \
  _Pragma("unroll")                                                     \
  for (int j = 0; j < 4; ++j) {                                         \
    buf[2 * j]     = LOADC(hq + ((cc) * 4 + j) * 8);                    \
    buf[2 * j + 1] = LOADC(hq + ((cc) * 4 + j) * 8 + 1);                \
  }
#define MFMA4(buf, cc)                                                  \
  _Pragma("unroll")                                                     \
  for (int j = 0; j < 4; ++j) {                                         \
    int k0 = (((cc) * 4 + j) << 5) + lk;                                \
    union { unsigned long long q[2]; bf16x8 v; } ua;                    \
    ua.q[0] = buf[2 * j]; ua.q[1] = buf[2 * j + 1];                     \
    _Pragma("unroll")                                                   \
    for (int nf = 0; nf < 4; ++nf) {                                    \
      int n = nf * 16 + lrow;                                           \
      unsigned byt = (unsigned)((n << 11) + (k0 << 1)) ^ ((unsigned)(n & 7) << 4); \
      bf16x8 b = *(const bf16x8*)(&lds[byt]);                           \
      acc[nf] = __builtin_amdgcn_mfma_f32_16x16x32_bf16(ua.v, b, acc[nf], 0, 0, 0); \
    }                                                                   \
  }

// ---------------- persistent dataflow LSTM (no grid barrier, no fences) ----------------
// blocks 0..63: h-blocks (own 16 h-cols = 64 gate-cols). blocks 64..191: x-blocks.
// All cross-block traffic via agent-scope (sc1) loads/stores: writers write-through
// to LLC, readers bypass L1/L2 -> no acquire fence, L2 never invalidated.
// hflag[b] = steps completed by h-block b. xflag[j] = steps produced by x-block j.
// xg ring: DEPTH slots; h step t reads slot t&7 (needs xflag[2wg..2wg+1] >= t+1);
// x step t writes slot t&7 (needs all hflag >= t-DEPTH+1, i.e. slot consumed).
// POLL DISCIPLINE (R9): only wave 0 of each block polls (s_sleep-paced); other
// waves park at __syncthreads -> poll traffic can't saturate LLC ports.
__global__ void __launch_bounds__(256, 1) lstm_main(
    const float* __restrict__ x,
    const __hip_bfloat16* __restrict__ wbih,
    const __hip_bfloat16* __restrict__ wbhh,
    const float* __restrict__ bias,
    __hip_bfloat16* __restrict__ hbuf,   // [2][B][H] bf16 ping-pong (sc1)
    float* __restrict__ xg,              // [DEPTH][B][4H] f32 ring (sc1)
    float* __restrict__ out,             // B*T*H + B*H + B*H
    unsigned* __restrict__ hflag,
    unsigned* __restrict__ xflag)
{
  extern __shared__ char lds[];
  float* gbuf = (float*)(lds + 131072);

  const int bid  = blockIdx.x;
  const bool is_h = (bid < NHB);
  const int tid  = threadIdx.x;
  const int lane = tid & 63;
  const int wave = tid >> 6;
  const int lrow = lane & 15;        // A row / B,D col within fragment
  const int lkg  = lane >> 4;        // 0..3
  const int lk   = lkg * 8;          // k offset within 32

  const int wg = is_h ? bid : ((bid - NHB) >> 1);   // gate-col slice 0..63
  const int rh = is_h ? 0 : ((bid - NHB) & 1);      // x row-half

  // ---- stage this block's 64x1024 weight slice into LDS (once, swizzled) ----
  {
    const __hip_bfloat16* wsrc = is_h ? wbhh : wbih;
    for (int c = tid; c < 8192; c += 256) {       // 8192 chunks of 16B = 128KB
      int n   = c >> 7;                           // local col 0..63
      int k16 = c & 127;                          // 16B chunk in k
      int gc  = ((n >> 4) << 10) + (wg << 4) + (n & 15);   // global gate row
      uint4 v = *(const uint4*)(wsrc + ((size_t)gc << 10) + (k16 << 3));
      unsigned byt = (unsigned)((n << 11) + (k16 << 4)) ^ ((unsigned)(n & 7) << 4);
      *(uint4*)(&lds[byt]) = v;
    }
  }
  __syncthreads();

  if (!is_h) {
    // ================= x-producer block: 32 rows x 64 gate-cols per step =================
    const int j  = bid - NHB;
    const int wr = wave & 1;       // 16-row tile within the 32-row half
    const int wc = wave >> 1;      // 32-col half
    const int arow = rh * 32 + wr * 16 + lrow;     // batch row for A loads
    const float* xa = x + (size_t)arow * (Tv * Iv) + lk;

    for (int t = 0; t < Tv; ++t) {
      if (t >= DEPTH) {            // slot t&7 must be consumed: all hflag >= t-DEPTH+1
        if (wave == 0) {
          const unsigned tgt = (unsigned)(t - DEPTH + 1);
          for (;;) {
            unsigned hf = LOADC(&hflag[lane * FSTR]);
            if (__all(hf >= tgt)) break;
            __builtin_amdgcn_s_sleep(4);   // ring-ahead: latency-insensitive
          }
        }
        __syncthreads();
        asm volatile("" ::: "memory");
      }
      f32x4 acc[2];
      acc[0] = f32x4{0.f,0.f,0.f,0.f}; acc[1] = f32x4{0.f,0.f,0.f,0.f};
      const float* xt = xa + (size_t)t * Iv;
      #pragma unroll 4
      for (int ks = 0; ks < 32; ++ks) {
        int k0 = (ks << 5) + lk;
        float4 f0 = *(const float4*)(xt + (ks << 5));
        float4 f1 = *(const float4*)(xt + (ks << 5) + 4);
        union { __hip_bfloat16 e[8]; bf16x8 v; } u;
        u.e[0] = __float2bfloat16(f0.x); u.e[1] = __float2bfloat16(f0.y);
        u.e[2] = __float2bfloat16(f0.z); u.e[3] = __float2bfloat16(f0.w);
        u.e[4] = __float2bfloat16(f1.x); u.e[5] = __float2bfloat16(f1.y);
        u.e[6] = __float2bfloat16(f1.z); u.e[7] = __float2bfloat16(f1.w);
        bf16x8 b0, b1;
        {
          int n = wc * 32 + lrow;
          unsigned byt = (unsigned)((n << 11) + (k0 << 1)) ^ ((unsigned)(n & 7) << 4);
          b0 = *(const bf16x8*)(&lds[byt]);
          n += 16;
          byt = (unsigned)((n << 11) + (k0 << 1)) ^ ((unsigned)(n & 7) << 4);
          b1 = *(const bf16x8*)(&lds[byt]);
        }
        acc[0] = __builtin_amdgcn_mfma_f32_16x16x32_bf16(u.v, b0, acc[0], 0, 0, 0);
        acc[1] = __builtin_amdgcn_mfma_f32_16x16x32_bf16(u.v, b1, acc[1], 0, 0, 0);
      }
      float* dst = xg + (size_t)(t & (DEPTH - 1)) * (Bv * G4v);
      for (int nf = 0; nf < 2; ++nf) {
        int gc  = (wc * 2 + nf) * 1024 + (wg << 4) + lrow;   // global gate col
        int row = rh * 32 + wr * 16 + (lkg << 2);
        for (int r = 0; r < 4; ++r)
          STOREC(&dst[(size_t)(row + r) * G4v + gc], acc[nf][r]);
      }
      asm volatile("s_waitcnt vmcnt(0)" ::: "memory");
      __syncthreads();
      if (tid == 0) STOREC(&xflag[j * FSTR], (unsigned)(t + 1));
      __syncthreads();
    }
    return;
  }

  // ================= h-recurrent block: full h x 64 gate-cols per step =================
  const int eb  = tid >> 2;            // batch row 0..63 (elementwise)
  const int ec0 = (tid & 3) << 2;      // h-col offset base within 16
  float c_state[4] = {0.f, 0.f, 0.f, 0.f};
  float biasv[16];
  for (int g = 0; g < 4; ++g)
    for (int jj = 0; jj < 4; ++jj)
      biasv[g * 4 + jj] = bias[(g << 10) + (wg << 4) + ec0 + jj];

  const int ar = wave * 16 + lrow;     // A row this lane loads (16 rows per wave)

  for (int t = 0; t < Tv; ++t) {
    // ---- poll (wave 0 only): all h-blocks done t-1; my 2 xg producers done t ----
    if (wave == 0) {
      const unsigned ht = (unsigned)t, xtg = (unsigned)(t + 1);
      const unsigned* xf = &xflag[(2 * wg + (lane & 1)) * FSTR];
      for (;;) {
        unsigned hf = LOADC(&hflag[lane * FSTR]);
        unsigned xv = LOADC(xf);
        if (__all(hf >= ht && xv >= xtg)) break;
        __builtin_amdgcn_s_sleep(1);
      }
    }
    __syncthreads();                   // waves 1-3 parked here: no poll traffic
    asm volatile("" ::: "memory");
    // ---- xg slice -> registers (sc1; in flight alongside the A chunks) ----
    float xgv[16];
    {
      const unsigned long long* xq = (const unsigned long long*)
          (xg + (size_t)(t & (DEPTH - 1)) * (Bv * G4v) + (size_t)eb * G4v + (wg << 4) + ec0);
      #pragma unroll
      for (int g = 0; g < 4; ++g) {
        union { unsigned long long q[2]; float f[4]; } ux;
        ux.q[0] = LOADC(xq + g * 512);
        ux.q[1] = LOADC(xq + g * 512 + 1);
        xgv[g * 4 + 0] = ux.f[0]; xgv[g * 4 + 1] = ux.f[1];
        xgv[g * 4 + 2] = ux.f[2]; xgv[g * 4 + 3] = ux.f[3];
      }
    }
    // ---- h GEMM: 2-buffer x 4-kstep A pipeline (8x8B sc1 loads per chunk) ----
    const __hip_bfloat16* hp = hbuf + (size_t)((t + 1) & 1) * (Bv * Hv);
    const unsigned long long* hq = (const unsigned long long*)hp + (size_t)ar * 256 + lkg * 2;
    f32x4 acc[4];
    for (int nf = 0; nf < 4; ++nf) acc[nf] = f32x4{0.f,0.f,0.f,0.f};
    {
      unsigned long long aqA[8], aqB[8];
      LOAD4(aqA, 0)
      LOAD4(aqB, 1)
      MFMA4(aqA, 0) LOAD4(aqA, 2)
      MFMA4(aqB, 1) LOAD4(aqB, 3)
      MFMA4(aqA, 2) LOAD4(aqA, 4)
      MFMA4(aqB, 3) LOAD4(aqB, 5)
      MFMA4(aqA, 4) LOAD4(aqA, 6)
      MFMA4(aqB, 5) LOAD4(aqB, 7)
      MFMA4(aqA, 6)
      MFMA4(aqB, 7)
    }
    // ---- exchange gates through LDS ----
    #pragma unroll
    for (int nf = 0; nf < 4; ++nf)
      for (int r = 0; r < 4; ++r)
        gbuf[(wave * 16 + (lkg << 2) + r) * 65 + nf * 16 + lrow] = acc[nf][r];
    __syncthreads();
    float hv[4];
    #pragma unroll
    for (int jj = 0; jj < 4; ++jj) {
      int cc = ec0 + jj;
      float g0 = gbuf[eb * 65 +      cc] + xgv[0 + jj]  + biasv[0 + jj];
      float g1 = gbuf[eb * 65 + 16 + cc] + xgv[4 + jj]  + biasv[4 + jj];
      float g2 = gbuf[eb * 65 + 32 + cc] + xgv[8 + jj]  + biasv[8 + jj];
      float g3 = gbuf[eb * 65 + 48 + cc] + xgv[12 + jj] + biasv[12 + jj];
      float ig = sigmoid_f(g0);
      float fg = sigmoid_f(g1);
      float gg = tanh_f(g2);
      float og = sigmoid_f(g3);
      float cv = fg * c_state[jj] + ig * gg;
      c_state[jj] = cv;
      hv[jj] = og * tanh_f(cv);
    }
    // publish h slice (one 8B sc1 store); drain covers ONLY this store
    __hip_bfloat16* hw = hbuf + (size_t)(t & 1) * (Bv * Hv) + ((size_t)eb << 10) + (wg << 4) + ec0;
    union { __hip_bfloat16 h[4]; unsigned long long q; } hu;
    for (int jj = 0; jj < 4; ++jj) hu.h[jj] = __float2bfloat16(hv[jj]);
    STOREC((unsigned long long*)hw, hu.q);
    asm volatile("s_waitcnt vmcnt(0)" ::: "memory");
    __syncthreads();                    // all waves' h stores at LLC
    if (tid == 0) STOREC(&hflag[wg * FSTR], (unsigned)(t + 1));
    // ---- out stores AFTER flag publish: HBM ack off the critical path ----
    float* ow = out + (size_t)eb * (Tv * Hv) + ((size_t)t << 10) + (wg << 4) + ec0;
    f32x4 ov = {hv[0], hv[1], hv[2], hv[3]};
    __builtin_nontemporal_store(ov, (f32x4*)ow);
    if (t == Tv - 1) {
      float* hn = out + (size_t)Bv * Tv * Hv + ((size_t)eb << 10) + (wg << 4) + ec0;
      float* cn = hn + (size_t)Bv * Hv;
      for (int jj = 0; jj < 4; ++jj) { hn[jj] = hv[jj]; cn[jj] = c_state[jj]; }
    }
    __syncthreads();
  }
}

// ---------------- host launch ----------------
extern "C" void kernel_launch(void* const* d_in, const int* in_sizes, int n_in,
                              void* d_out, int out_size, void* d_ws, size_t ws_size,
                              hipStream_t stream) {
  const float* x    = (const float*)d_in[0];
  const float* w_ih = (const float*)d_in[1];
  const float* b_ih = (const float*)d_in[2];
  const float* w_hh = (const float*)d_in[3];
  const float* b_hh = (const float*)d_in[4];
  float* out = (float*)d_out;

  char* ws = (char*)d_ws;
  __hip_bfloat16* wbih = (__hip_bfloat16*)(ws);                        // 8 MB
  __hip_bfloat16* wbhh = (__hip_bfloat16*)(ws + ((size_t)8 << 20));    // 8 MB
  float*          bias = (float*)(ws + ((size_t)16 << 20));            // 16 KB
  __hip_bfloat16* hbuf = (__hip_bfloat16*)(ws + ((size_t)16 << 20) + 65536); // 256 KB
  float*          xg   = (float*)(ws + ((size_t)18 << 20));            // 8 MB ring
  unsigned*       hflag= (unsigned*)(ws + ((size_t)26 << 20));         // 4 KB
  unsigned*       xflag= (unsigned*)(ws + ((size_t)26 << 20) + 8192);  // 8 KB

  hipLaunchKernelGGL(prep, dim3(16384), dim3(256), 0, stream,
                     w_ih, w_hh, b_ih, b_hh, wbih, wbhh, bias, hbuf, hflag, xflag);

  const unsigned ldsBytes = 131072u + 64u * 65u * 4u;  // 147712
  hipFuncSetAttribute((const void*)lstm_main,
                      hipFuncAttributeMaxDynamicSharedMemorySize, (int)ldsBytes);

  const float* xA = x;
  const __hip_bfloat16* wbihA = wbih;
  const __hip_bfloat16* wbhhA = wbhh;
  const float* biasA = bias;
  __hip_bfloat16* hbufA = hbuf;
  float* xgA = xg;
  float* outA = out;
  unsigned* hflagA = hflag;
  unsigned* xflagA = xflag;
  void* args[9] = {(void*)&xA, (void*)&wbihA, (void*)&wbhhA, (void*)&biasA,
                   (void*)&hbufA, (void*)&xgA, (void*)&outA, (void*)&hflagA, (void*)&xflagA};

  // Cooperative launch guarantees co-residency, but its validation can reject
  // silently (R5/R6 zero-output signature). Our sync protocol uses only our own
  // flags (no cg::grid.sync), and 147712B LDS forces 1 block/CU so 192 blocks
  // co-reside under a plain launch too. Fall back if coop launch errors.
  hipError_t lerr = hipLaunchCooperativeKernel((const void*)lstm_main, dim3(NBLK),
                                               dim3(256), args, ldsBytes, stream);
  if (lerr != hipSuccess) {
    (void)hipGetLastError();   // clear sticky error, then plain launch
    hipLaunchKernelGGL(lstm_main, dim3(NBLK), dim3(256), ldsBytes, stream,
                       xA, wbihA, wbhhA, biasA, hbufA, xgA, outA, hflagA, xflagA);
  }
}

// Round 10
// 4597.017 us; speedup vs baseline: 1.4255x; 1.1610x over previous
//
#include <hip/hip_runtime.h>
#include <hip/hip_bf16.h>

#define Bv 64
#define Tv 512
#define Iv 1024
#define Hv 1024
#define G4v 4096
#define BH (Bv * Hv)
#define NHB 64          // recurrent blocks
#define NXB 128         // producer blocks (2 per 64-col slice, row-split)
#define NBLK (NHB + NXB)
#define DEPTH 8         // xg ring depth (power of 2)
#define FSTR 16         // flag padding: 64B

typedef __attribute__((ext_vector_type(8))) short bf16x8;
typedef __attribute__((ext_vector_type(4))) float f32x4;

#define LOADC(p)    __hip_atomic_load((p), __ATOMIC_RELAXED, __HIP_MEMORY_SCOPE_AGENT)
#define STOREC(p,v) __hip_atomic_store((p), (v), __ATOMIC_RELAXED, __HIP_MEMORY_SCOPE_AGENT)

__device__ __forceinline__ float sigmoid_f(float v) { return 1.f / (1.f + __expf(-v)); }
__device__ __forceinline__ float tanh_f(float v) { return 1.f - 2.f / (__expf(2.f * v) + 1.f); }

// ---------------- prep: weights -> bf16, bias sum, zero h slots 0-1 + flags ----------------
__global__ void prep(const float* __restrict__ w_ih, const float* __restrict__ w_hh,
                     const float* __restrict__ b_ih, const float* __restrict__ b_hh,
                     __hip_bfloat16* __restrict__ wbih, __hip_bfloat16* __restrict__ wbhh,
                     float* __restrict__ bias, __hip_bfloat16* __restrict__ hbuf,
                     unsigned* __restrict__ hflag, unsigned* __restrict__ xflag) {
  unsigned i = blockIdx.x * 256u + threadIdx.x;   // grid covers exactly 4096*1024
  wbih[i] = __float2bfloat16(w_ih[i]);
  wbhh[i] = __float2bfloat16(w_hh[i]);
  if (i < (unsigned)G4v) bias[i] = b_ih[i] + b_hh[i];
  if (i < 2u * BH) hbuf[i] = __float2bfloat16(0.f);   // ring slots 0-1 / pingpong both
  if (i < (unsigned)(NHB * FSTR)) hflag[i] = 0u;
  if (i < (unsigned)(NXB * FSTR)) xflag[i] = 0u;
}

// ---- fallback (sc1 pingpong) A pipeline: R9-exact 2-deep chunked macros ----
#define LOAD4(buf, cc)                                                  \
  _Pragma("unroll")                                                     \
  for (int j = 0; j < 4; ++j) {                                         \
    buf[2 * j]     = LOADC(hq + ((cc) * 4 + j) * 8);                    \
    buf[2 * j + 1] = LOADC(hq + ((cc) * 4 + j) * 8 + 1);                \
  }
#define MFMA4(buf, cc)                                                  \
  _Pragma("unroll")                                                     \
  for (int j = 0; j < 4; ++j) {                                         \
    int k0 = (((cc) * 4 + j) << 5) + lk;                                \
    union { unsigned long long q[2]; bf16x8 v; } ua;                    \
    ua.q[0] = buf[2 * j]; ua.q[1] = buf[2 * j + 1];                     \
    _Pragma("unroll")                                                   \
    for (int nf = 0; nf < 4; ++nf) {                                    \
      int n = nf * 16 + lrow;                                           \
      unsigned byt = (unsigned)((n << 11) + (k0 << 1)) ^ ((unsigned)(n & 7) << 4); \
      bf16x8 b = *(const bf16x8*)(&lds[byt]);                           \
      acc[nf] = __builtin_amdgcn_mfma_f32_16x16x32_bf16(ua.v, b, acc[nf], 0, 0, 0); \
    }                                                                   \
  }

// ---------------- persistent dataflow LSTM (no grid barrier, no fences) ----------------
// blocks 0..63: h-blocks; blocks 64..191: x-producer blocks (R9 structure).
// RING MODE (ws permitting): hbuf is a [Tv+1][B][H] bf16 ring. Step t READS slot t
// with NORMAL CACHED loads (virgin address each step -> staleness impossible; 8
// blocks/XCD share the lines in L2) and WRITES slot t+1 with sc1 write-through.
// A-loads are a single 32x16B burst -> ONE exposed LLC round trip (R8 retest,
// now with wave0-only polls). Fallback mode = R9-exact sc1 pingpong pipeline.
__global__ void __launch_bounds__(256, 1) lstm_main(
    const float* __restrict__ x,
    const __hip_bfloat16* __restrict__ wbih,
    const __hip_bfloat16* __restrict__ wbhh,
    const float* __restrict__ bias,
    __hip_bfloat16* __restrict__ hbuf,   // ring [Tv+1][B][H] or pingpong [2][B][H]
    float* __restrict__ xg,              // [DEPTH][B][4H] f32 ring (sc1)
    float* __restrict__ out,             // B*T*H + B*H + B*H
    unsigned* __restrict__ hflag,
    unsigned* __restrict__ xflag,
    int ring)
{
  extern __shared__ char lds[];
  float* gbuf = (float*)(lds + 131072);

  const int bid  = blockIdx.x;
  const bool is_h = (bid < NHB);
  const int tid  = threadIdx.x;
  const int lane = tid & 63;
  const int wave = tid >> 6;
  const int lrow = lane & 15;        // A row / B,D col within fragment
  const int lkg  = lane >> 4;        // 0..3
  const int lk   = lkg * 8;          // k offset within 32

  const int wg = is_h ? bid : ((bid - NHB) >> 1);   // gate-col slice 0..63
  const int rh = is_h ? 0 : ((bid - NHB) & 1);      // x row-half

  // ---- stage this block's 64x1024 weight slice into LDS (once, swizzled) ----
  {
    const __hip_bfloat16* wsrc = is_h ? wbhh : wbih;
    for (int c = tid; c < 8192; c += 256) {       // 8192 chunks of 16B = 128KB
      int n   = c >> 7;                           // local col 0..63
      int k16 = c & 127;                          // 16B chunk in k
      int gc  = ((n >> 4) << 10) + (wg << 4) + (n & 15);   // global gate row
      uint4 v = *(const uint4*)(wsrc + ((size_t)gc << 10) + (k16 << 3));
      unsigned byt = (unsigned)((n << 11) + (k16 << 4)) ^ ((unsigned)(n & 7) << 4);
      *(uint4*)(&lds[byt]) = v;
    }
  }
  __syncthreads();

  if (!is_h) {
    // ================= x-producer block (R9-exact) =================
    const int j  = bid - NHB;
    const int wr = wave & 1;
    const int wc = wave >> 1;
    const int arow = rh * 32 + wr * 16 + lrow;
    const float* xa = x + (size_t)arow * (Tv * Iv) + lk;

    for (int t = 0; t < Tv; ++t) {
      if (t >= DEPTH) {
        if (wave == 0) {
          const unsigned tgt = (unsigned)(t - DEPTH + 1);
          for (;;) {
            unsigned hf = LOADC(&hflag[lane * FSTR]);
            if (__all(hf >= tgt)) break;
            __builtin_amdgcn_s_sleep(4);
          }
        }
        __syncthreads();
        asm volatile("" ::: "memory");
      }
      f32x4 acc[2];
      acc[0] = f32x4{0.f,0.f,0.f,0.f}; acc[1] = f32x4{0.f,0.f,0.f,0.f};
      const float* xt = xa + (size_t)t * Iv;
      #pragma unroll 4
      for (int ks = 0; ks < 32; ++ks) {
        int k0 = (ks << 5) + lk;
        float4 f0 = *(const float4*)(xt + (ks << 5));
        float4 f1 = *(const float4*)(xt + (ks << 5) + 4);
        union { __hip_bfloat16 e[8]; bf16x8 v; } u;
        u.e[0] = __float2bfloat16(f0.x); u.e[1] = __float2bfloat16(f0.y);
        u.e[2] = __float2bfloat16(f0.z); u.e[3] = __float2bfloat16(f0.w);
        u.e[4] = __float2bfloat16(f1.x); u.e[5] = __float2bfloat16(f1.y);
        u.e[6] = __float2bfloat16(f1.z); u.e[7] = __float2bfloat16(f1.w);
        bf16x8 b0, b1;
        {
          int n = wc * 32 + lrow;
          unsigned byt = (unsigned)((n << 11) + (k0 << 1)) ^ ((unsigned)(n & 7) << 4);
          b0 = *(const bf16x8*)(&lds[byt]);
          n += 16;
          byt = (unsigned)((n << 11) + (k0 << 1)) ^ ((unsigned)(n & 7) << 4);
          b1 = *(const bf16x8*)(&lds[byt]);
        }
        acc[0] = __builtin_amdgcn_mfma_f32_16x16x32_bf16(u.v, b0, acc[0], 0, 0, 0);
        acc[1] = __builtin_amdgcn_mfma_f32_16x16x32_bf16(u.v, b1, acc[1], 0, 0, 0);
      }
      float* dst = xg + (size_t)(t & (DEPTH - 1)) * (Bv * G4v);
      for (int nf = 0; nf < 2; ++nf) {
        int gc  = (wc * 2 + nf) * 1024 + (wg << 4) + lrow;
        int row = rh * 32 + wr * 16 + (lkg << 2);
        for (int r = 0; r < 4; ++r)
          STOREC(&dst[(size_t)(row + r) * G4v + gc], acc[nf][r]);
      }
      asm volatile("s_waitcnt vmcnt(0)" ::: "memory");
      __syncthreads();
      if (tid == 0) STOREC(&xflag[j * FSTR], (unsigned)(t + 1));
      __syncthreads();
    }
    return;
  }

  // ================= h-recurrent block =================
  const int eb  = tid >> 2;
  const int ec0 = (tid & 3) << 2;
  float c_state[4] = {0.f, 0.f, 0.f, 0.f};
  float biasv[16];
  for (int g = 0; g < 4; ++g)
    for (int jj = 0; jj < 4; ++jj)
      biasv[g * 4 + jj] = bias[(g << 10) + (wg << 4) + ec0 + jj];

  const int ar = wave * 16 + lrow;     // A row this lane loads

  for (int t = 0; t < Tv; ++t) {
    // ---- poll (wave 0 only, R9): all h-blocks done t-1; my 2 producers done t ----
    if (wave == 0) {
      const unsigned ht = (unsigned)t, xtg = (unsigned)(t + 1);
      const unsigned* xf = &xflag[(2 * wg + (lane & 1)) * FSTR];
      for (;;) {
        unsigned hf = LOADC(&hflag[lane * FSTR]);
        unsigned xv = LOADC(xf);
        if (__all(hf >= ht && xv >= xtg)) break;
        __builtin_amdgcn_s_sleep(1);
      }
    }
    __syncthreads();
    asm volatile("" ::: "memory");
    // ---- xg slice -> registers (sc1; overlaps the A phase) ----
    float xgv[16];
    {
      const unsigned long long* xq = (const unsigned long long*)
          (xg + (size_t)(t & (DEPTH - 1)) * (Bv * G4v) + (size_t)eb * G4v + (wg << 4) + ec0);
      #pragma unroll
      for (int g = 0; g < 4; ++g) {
        union { unsigned long long q[2]; float f[4]; } ux;
        ux.q[0] = LOADC(xq + g * 512);
        ux.q[1] = LOADC(xq + g * 512 + 1);
        xgv[g * 4 + 0] = ux.f[0]; xgv[g * 4 + 1] = ux.f[1];
        xgv[g * 4 + 2] = ux.f[2]; xgv[g * 4 + 3] = ux.f[3];
      }
    }
    f32x4 acc[4];
    for (int nf = 0; nf < 4; ++nf) acc[nf] = f32x4{0.f,0.f,0.f,0.f};
    if (ring) {
      // ---- RING: normal cached 16B loads from virgin slot t, FULL burst ----
      // One exposed LLC trip; 7 of 8 blocks/XCD then hit L2 on shared lines.
      const __hip_bfloat16* hp2 = hbuf + (size_t)t * BH;
      const char* hrow = (const char*)hp2 + ((size_t)ar << 11) + (lkg << 4);
      bf16x8 aqv[32];
      #pragma unroll
      for (int ks = 0; ks < 32; ++ks)
        aqv[ks] = *(const bf16x8*)(hrow + (ks << 6));
      #pragma unroll
      for (int ks = 0; ks < 32; ++ks) {
        int k0 = (ks << 5) + lk;
        #pragma unroll
        for (int nf = 0; nf < 4; ++nf) {
          int n = nf * 16 + lrow;
          unsigned byt = (unsigned)((n << 11) + (k0 << 1)) ^ ((unsigned)(n & 7) << 4);
          bf16x8 b = *(const bf16x8*)(&lds[byt]);
          acc[nf] = __builtin_amdgcn_mfma_f32_16x16x32_bf16(aqv[ks], b, acc[nf], 0, 0, 0);
        }
      }
    } else {
      // ---- FALLBACK: R9-exact sc1 pingpong, 2-deep chunked pipeline ----
      const __hip_bfloat16* hp = hbuf + (size_t)((t + 1) & 1) * BH;
      const unsigned long long* hq = (const unsigned long long*)hp + (size_t)ar * 256 + lkg * 2;
      unsigned long long aqA[8], aqB[8];
      LOAD4(aqA, 0)
      LOAD4(aqB, 1)
      MFMA4(aqA, 0) LOAD4(aqA, 2)
      MFMA4(aqB, 1) LOAD4(aqB, 3)
      MFMA4(aqA, 2) LOAD4(aqA, 4)
      MFMA4(aqB, 3) LOAD4(aqB, 5)
      MFMA4(aqA, 4) LOAD4(aqA, 6)
      MFMA4(aqB, 5) LOAD4(aqB, 7)
      MFMA4(aqA, 6)
      MFMA4(aqB, 7)
    }
    // ---- exchange gates through LDS ----
    #pragma unroll
    for (int nf = 0; nf < 4; ++nf)
      for (int r = 0; r < 4; ++r)
        gbuf[(wave * 16 + (lkg << 2) + r) * 65 + nf * 16 + lrow] = acc[nf][r];
    __syncthreads();
    float hv[4];
    #pragma unroll
    for (int jj = 0; jj < 4; ++jj) {
      int cc = ec0 + jj;
      float g0 = gbuf[eb * 65 +      cc] + xgv[0 + jj]  + biasv[0 + jj];
      float g1 = gbuf[eb * 65 + 16 + cc] + xgv[4 + jj]  + biasv[4 + jj];
      float g2 = gbuf[eb * 65 + 32 + cc] + xgv[8 + jj]  + biasv[8 + jj];
      float g3 = gbuf[eb * 65 + 48 + cc] + xgv[12 + jj] + biasv[12 + jj];
      float ig = sigmoid_f(g0);
      float fg = sigmoid_f(g1);
      float gg = tanh_f(g2);
      float og = sigmoid_f(g3);
      float cv = fg * c_state[jj] + ig * gg;
      c_state[jj] = cv;
      hv[jj] = og * tanh_f(cv);
    }
    // publish h slice (one 8B sc1 write-through store)
    __hip_bfloat16* hw = hbuf
        + (ring ? (size_t)(t + 1) * BH : (size_t)(t & 1) * BH)
        + ((size_t)eb << 10) + (wg << 4) + ec0;
    union { __hip_bfloat16 h[4]; unsigned long long q; } hu;
    for (int jj = 0; jj < 4; ++jj) hu.h[jj] = __float2bfloat16(hv[jj]);
    STOREC((unsigned long long*)hw, hu.q);
    asm volatile("s_waitcnt vmcnt(0)" ::: "memory");
    __syncthreads();                    // all waves' h stores at LLC
    if (tid == 0) STOREC(&hflag[wg * FSTR], (unsigned)(t + 1));
    // ---- out stores AFTER flag publish: HBM ack off the critical path ----
    float* ow = out + (size_t)eb * (Tv * Hv) + ((size_t)t << 10) + (wg << 4) + ec0;
    f32x4 ov = {hv[0], hv[1], hv[2], hv[3]};
    __builtin_nontemporal_store(ov, (f32x4*)ow);
    if (t == Tv - 1) {
      float* hn = out + (size_t)Bv * Tv * Hv + ((size_t)eb << 10) + (wg << 4) + ec0;
      float* cn = hn + (size_t)Bv * Hv;
      for (int jj = 0; jj < 4; ++jj) { hn[jj] = hv[jj]; cn[jj] = c_state[jj]; }
    }
    __syncthreads();
  }
}

// ---------------- host launch ----------------
extern "C" void kernel_launch(void* const* d_in, const int* in_sizes, int n_in,
                              void* d_out, int out_size, void* d_ws, size_t ws_size,
                              hipStream_t stream) {
  const float* x    = (const float*)d_in[0];
  const float* w_ih = (const float*)d_in[1];
  const float* b_ih = (const float*)d_in[2];
  const float* w_hh = (const float*)d_in[3];
  const float* b_hh = (const float*)d_in[4];
  float* out = (float*)d_out;

  char* ws = (char*)d_ws;
  __hip_bfloat16* wbih = (__hip_bfloat16*)(ws);                        // 8 MB
  __hip_bfloat16* wbhh = (__hip_bfloat16*)(ws + ((size_t)8 << 20));    // 8 MB
  float*          bias = (float*)(ws + ((size_t)16 << 20));            // 16 KB
  float*          xg   = (float*)(ws + ((size_t)18 << 20));            // 8 MB ring
  unsigned*       hflag= (unsigned*)(ws + ((size_t)26 << 20));         // 4 KB
  unsigned*       xflag= (unsigned*)(ws + ((size_t)26 << 20) + 8192);  // 8 KB

  // ring mode: hbuf = [Tv+1][B][H] bf16 at 32MB (needs ~96.1MB total ws)
  const size_t ringBytes = (size_t)(Tv + 1) * BH * 2;
  const size_t needRing  = ((size_t)32 << 20) + ringBytes;
  const int ring = (ws_size >= needRing) ? 1 : 0;
  __hip_bfloat16* hbuf = ring
      ? (__hip_bfloat16*)(ws + ((size_t)32 << 20))
      : (__hip_bfloat16*)(ws + ((size_t)16 << 20) + 65536);

  hipLaunchKernelGGL(prep, dim3(16384), dim3(256), 0, stream,
                     w_ih, w_hh, b_ih, b_hh, wbih, wbhh, bias, hbuf, hflag, xflag);

  const unsigned ldsBytes = 131072u + 64u * 65u * 4u;  // 147712
  hipFuncSetAttribute((const void*)lstm_main,
                      hipFuncAttributeMaxDynamicSharedMemorySize, (int)ldsBytes);

  const float* xA = x;
  const __hip_bfloat16* wbihA = wbih;
  const __hip_bfloat16* wbhhA = wbhh;
  const float* biasA = bias;
  __hip_bfloat16* hbufA = hbuf;
  float* xgA = xg;
  float* outA = out;
  unsigned* hflagA = hflag;
  unsigned* xflagA = xflag;
  int ringA = ring;
  void* args[10] = {(void*)&xA, (void*)&wbihA, (void*)&wbhhA, (void*)&biasA,
                    (void*)&hbufA, (void*)&xgA, (void*)&outA, (void*)&hflagA,
                    (void*)&xflagA, (void*)&ringA};

  // Coop launch can reject silently (R5/R6). Our sync is flag-based only and
  // 147712B LDS forces 1 block/CU -> plain launch co-resides too. Fall back.
  hipError_t lerr = hipLaunchCooperativeKernel((const void*)lstm_main, dim3(NBLK),
                                               dim3(256), args, ldsBytes, stream);
  if (lerr != hipSuccess) {
    (void)hipGetLastError();   // clear sticky error, then plain launch
    hipLaunchKernelGGL(lstm_main, dim3(NBLK), dim3(256), ldsBytes, stream,
                       xA, wbihA, wbhhA, biasA, hbufA, xgA, outA, hflagA, xflagA, ringA);
  }
}